// Round 13
// baseline (72.300 us; speedup 1.0000x reference)
//
#include <hip/hip_runtime.h>

// BayesTensorRing via MFMA: out[s] = trace(M0'·M1'·M2'·M3'), Md' = core_d[idx_d]·diag(lam_d).
// ranks 16, dims 200, N = 500000. One sample = one wave-step; 64 samples per wave.
//
// R13 restructure: trace = sum_{m,n} X[m][n]*Z[m][n] with
//   X = M0'·M1'        = mfma(A=W0 frag, B=W1^T frag)   (D-layout [4(l>>4)+i][l&15])
//   Z = (M2'·M3')^T    = mfma(A=W3^T frag, B=W2 frag)   (same layout position)
// -> TWO INDEPENDENT MFMAs (no serial mfma->cvt->mfma chain, no f16 intermediate),
//    then per-lane 4-term dot + 6-step DPP funnel -> lane 63.
// All four operand fragments use the SAME per-lane offset hoff = (l&15)*16+4*(l>>4).
//
// Pipeline is forced with inline asm (R9-R12: hipcc collapsed every source-level
// pipeline, VGPR=20..28): global_load_dwordx2 with SGPR base (readlane -> SALU) +
// loop-invariant per-lane voffset, 4 states x 4 loads = 16 outstanding, counted
// s_waitcnt vmcnt(12) + sched_barrier(0) before each state's MFMAs (rule #18).
//
// ws: W0 f16 M0' row-major @0 | W1 f16 M1'^T @102400 | W2 f16 M2' row-major @204800 |
//     W3 f16 M3'^T @307200. Total 409600 B.

typedef _Float16 f16x4 __attribute__((ext_vector_type(4)));
typedef _Float16 f16x2 __attribute__((ext_vector_type(2)));
typedef float    f32x4 __attribute__((ext_vector_type(4)));

#define DEV static __device__ __forceinline__

template<int CTRL>
DEV float dppmov(float x)
{
    return __int_as_float(__builtin_amdgcn_update_dpp(
        0, __float_as_int(x), CTRL, 0xF, 0xF, true));
}

// pinned 8B gather: SGPR base + 32-bit VGPR byte offset (saddr form)
DEV f16x4 ldg8s(const _Float16* sbase, int voff)
{
    f16x4 d;
    asm volatile("global_load_dwordx2 %0, %1, %2"
                 : "=&v"(d) : "v"(voff), "s"(sbase) : "memory");
    return d;
}

#define WAITV(N) asm volatile("s_waitcnt vmcnt(" #N ")" ::: "memory")

__global__ __launch_bounds__(256)
void mfma_chain(const int* __restrict__ idx, const char* __restrict__ wsb,
                float* __restrict__ out, int n)
{
    const _Float16* W0 = (const _Float16*)(wsb);
    const _Float16* W1 = (const _Float16*)(wsb + 102400);
    const _Float16* W2 = (const _Float16*)(wsb + 204800);
    const _Float16* W3 = (const _Float16*)(wsb + 307200);

    const int lane = threadIdx.x & 63;
    const int wv   = (blockIdx.x << 2) | (threadIdx.x >> 6);
    const int s0   = __builtin_amdgcn_readfirstlane(wv << 6);   // uniform wave base
    if (s0 >= n) return;
    const int cnt  = (n - s0 < 64) ? (n - s0) : 64;             // 64 or 32 here

    // per-lane fragment byte offset, identical for all four matrices (loop-invariant)
    const int hoff = ((lane & 15) << 4) + ((lane >> 4) << 2);   // element index
    const int voff = hoff * 2;                                  // bytes (f16)

    // preload this wave's 64 idx rows: lane l holds sample s0+min(l,cnt-1)
    const int lc = lane < cnt ? lane : cnt - 1;
    const int4 vidx = *(const int4*)(idx + 4l * (s0 + lc));

    float res = 0.f;

    // issue the 4 gathers for sample t of state S (uniform SGPR bases via readlane)
    #define ISSUE(S, t) {                                                   \
        const int tt = (t) < 63 ? (t) : 63;                                 \
        const int i0 = __builtin_amdgcn_readlane(vidx.x, tt);               \
        const int i1 = __builtin_amdgcn_readlane(vidx.y, tt);               \
        const int i2 = __builtin_amdgcn_readlane(vidx.z, tt);               \
        const int i3 = __builtin_amdgcn_readlane(vidx.w, tt);               \
        S##a0 = ldg8s(W0 + i0 * 256, voff);                                 \
        S##b1 = ldg8s(W1 + i1 * 256, voff);                                 \
        S##b2 = ldg8s(W2 + i2 * 256, voff);                                 \
        S##a3 = ldg8s(W3 + i3 * 256, voff);                                 \
    }

    // consume state S = sample t: wait its 4 loads (oldest 4 of 16) -> 2 indep MFMAs
    // -> 4-term dot -> DPP funnel -> select into res[lane==t]
    #define COMP(S, t) {                                                    \
        WAITV(12);                                                          \
        __builtin_amdgcn_sched_barrier(0);                                  \
        const f32x4 z = {0.f, 0.f, 0.f, 0.f};                               \
        f32x4 X = __builtin_amdgcn_mfma_f32_16x16x16f16(S##a0, S##b1, z, 0, 0, 0); \
        f32x4 Z = __builtin_amdgcn_mfma_f32_16x16x16f16(S##a3, S##b2, z, 0, 0, 0); \
        float p =       X[0] * Z[0];                                        \
        p = fmaf(X[1], Z[1], p);                                            \
        p = fmaf(X[2], Z[2], p);                                            \
        p = fmaf(X[3], Z[3], p);                                            \
        p += dppmov<0x111>(p);                                              \
        p += dppmov<0x112>(p);                                              \
        p += dppmov<0x114>(p);                                              \
        p += dppmov<0x118>(p);                                              \
        p += dppmov<0x142>(p);                                              \
        p += dppmov<0x143>(p);                                              \
        const int pv = __builtin_amdgcn_readlane(__float_as_int(p), 63);    \
        res = (lane == (t)) ? __int_as_float(pv) : res;                     \
    }

    f16x4 Aa0, Ab1, Ab2, Aa3;
    f16x4 Ba0, Bb1, Bb2, Ba3;
    f16x4 Ca0, Cb1, Cb2, Ca3;
    f16x4 Da0, Db1, Db2, Da3;

    ISSUE(A, 0); ISSUE(B, 1); ISSUE(C, 2); ISSUE(D, 3);

    const int cntR = (cnt + 3) & ~3;     // 64 or 32
    for (int t = 0; t + 4 <= cntR; t += 4) {
        COMP(A, t);     ISSUE(A, t + 4);
        COMP(B, t + 1); ISSUE(B, t + 5);
        COMP(C, t + 2); ISSUE(C, t + 6);
        COMP(D, t + 3); ISSUE(D, t + 7);
    }

    if (lane < cnt) out[s0 + lane] = res;   // one coalesced store per wave

    #undef ISSUE
    #undef COMP
}

// Prescale + reformat cores into ws (all f16: W0 rm, W1^T, W2 rm, W3^T). 400 x 256.
__global__ __launch_bounds__(256)
void prescale_kernel(const float* __restrict__ cr0, const float* __restrict__ lm0,
                     const float* __restrict__ cr1, const float* __restrict__ lm1,
                     const float* __restrict__ cr2, const float* __restrict__ lm2,
                     const float* __restrict__ cr3, const float* __restrict__ lm3,
                     char* __restrict__ wsb)
{
    _Float16* W0 = (_Float16*)(wsb);
    _Float16* W1 = (_Float16*)(wsb + 102400);
    _Float16* W2 = (_Float16*)(wsb + 204800);
    _Float16* W3 = (_Float16*)(wsb + 307200);

    const int bx  = blockIdx.x;          // 0..399
    const int d   = bx / 100;            // matrix id (uniform per block)
    const int gid = (bx % 100) * 256 + threadIdx.x;   // 0..25599
    const int i   = gid >> 7;            // slice 0..199
    const int pr  = gid & 127;           // pair id 0..127

    if (d == 0 || d == 2) {
        const float* cp = (d == 0) ? cr0 : cr2;
        const float* lp = (d == 0) ? lm0 : lm2;
        _Float16*    Wt = (d == 0) ? W0 : W2;
        const int r = pr >> 3, c = (pr & 7) * 2;      // row-major store
        const float2 v = *(const float2*)(cp + i * 256 + r * 16 + c);
        f16x2 o; o[0] = (_Float16)(v.x * lp[c]); o[1] = (_Float16)(v.y * lp[c + 1]);
        *(f16x2*)(Wt + i * 256 + r * 16 + c) = o;
    } else {
        const float* cp = (d == 1) ? cr1 : cr3;
        const float* lp = (d == 1) ? lm1 : lm3;
        _Float16*    Wt = (d == 1) ? W1 : W3;
        const int c = pr >> 3, r = (pr & 7) * 2;      // transposed store: pos c*16 + r
        const float a = cp[i * 256 + r * 16 + c]       * lp[c];
        const float b = cp[i * 256 + (r + 1) * 16 + c] * lp[c];
        f16x2 o; o[0] = (_Float16)a; o[1] = (_Float16)b;
        *(f16x2*)(Wt + i * 256 + c * 16 + r) = o;
    }
}

// ---------------- fallback (no workspace): R5 DPP vector kernel ----------------
template<int CTRL>
DEV float dppf(float x)
{
    return __int_as_float(__builtin_amdgcn_update_dpp(
        0, __float_as_int(x), CTRL, 0xF, 0xF, true));
}

DEV void mm16g_lam(const float (&a)[4][16], float (&b)[4][16],
                   const float* __restrict__ m, const float* __restrict__ lam)
{
    const float4* m4 = reinterpret_cast<const float4*>(m);
    float4 lv[4];
#pragma unroll
    for (int q = 0; q < 4; ++q) lv[q] = reinterpret_cast<const float4*>(lam)[q];
#pragma unroll
    for (int nn = 0; nn < 16; ++nn) {
        float mrow[16];
#pragma unroll
        for (int q = 0; q < 4; ++q) {
            float4 v = m4[4 * nn + q];
            v.x *= lv[q].x; v.y *= lv[q].y; v.z *= lv[q].z; v.w *= lv[q].w;
            mrow[4*q+0] = v.x; mrow[4*q+1] = v.y;
            mrow[4*q+2] = v.z; mrow[4*q+3] = v.w;
        }
#pragma unroll
        for (int r = 0; r < 4; ++r) {
            const float av = a[r][nn];
            if (nn == 0) {
#pragma unroll
                for (int k = 0; k < 16; ++k) b[r][k] = av * mrow[k];
            } else {
#pragma unroll
                for (int k = 0; k < 16; ++k) b[r][k] = fmaf(av, mrow[k], b[r][k]);
            }
        }
    }
}

__global__ __launch_bounds__(256)
void chain_kernel_fb(const int* __restrict__ idx,
                     const float* __restrict__ c0, const float* __restrict__ l0,
                     const float* __restrict__ c1, const float* __restrict__ l1,
                     const float* __restrict__ c2, const float* __restrict__ l2,
                     const float* __restrict__ c3, const float* __restrict__ l3,
                     float* __restrict__ out, int n)
{
    const int tid  = threadIdx.x;
    const int slot = tid >> 2;
    const int j    = tid & 3;
    const int s    = blockIdx.x * 64 + slot;
    const int sc   = s < n ? s : n - 1;

    const int4 ix = *reinterpret_cast<const int4*>(idx + 4l * sc);

    float a[4][16], b[4][16];
    {
        const float4* src = reinterpret_cast<const float4*>(c0 + 256l * ix.x) + 16 * j;
#pragma unroll
        for (int t = 0; t < 16; ++t) {
            float4 v = src[t];
            const float4 L = reinterpret_cast<const float4*>(l0)[t & 3];
            const int r = t >> 2, c = (t & 3) * 4;
            a[r][c+0] = v.x * L.x; a[r][c+1] = v.y * L.y;
            a[r][c+2] = v.z * L.z; a[r][c+3] = v.w * L.w;
        }
    }

    mm16g_lam(a, b, c1 + 256l * ix.y, l1);
    mm16g_lam(b, a, c2 + 256l * ix.z, l2);

    float4 part = make_float4(0.f, 0.f, 0.f, 0.f);
    const float* base3 = c3 + 256l * ix.w + 4 * j;
#pragma unroll
    for (int nn = 0; nn < 16; ++nn) {
        const float4 v = *reinterpret_cast<const float4*>(base3 + 16 * nn);
        part.x = fmaf(a[0][nn], v.x, part.x);
        part.y = fmaf(a[1][nn], v.y, part.y);
        part.z = fmaf(a[2][nn], v.z, part.z);
        part.w = fmaf(a[3][nn], v.w, part.w);
    }
    const float4 L3 = reinterpret_cast<const float4*>(l3)[j];
    float p = part.x * L3.x + part.y * L3.y + part.z * L3.z + part.w * L3.w;

    p += __shfl_xor(p, 1);
    p += __shfl_xor(p, 2);

    if (s < n && j == 0) out[s] = p;
}

extern "C" void kernel_launch(void* const* d_in, const int* in_sizes, int n_in,
                              void* d_out, int out_size, void* d_ws, size_t ws_size,
                              hipStream_t stream)
{
    const int*   idx = (const int*)  d_in[0];
    const float* c0  = (const float*)d_in[1];
    const float* l0  = (const float*)d_in[2];
    const float* c1  = (const float*)d_in[3];
    const float* l1  = (const float*)d_in[4];
    const float* c2  = (const float*)d_in[5];
    const float* l2  = (const float*)d_in[6];
    const float* c3  = (const float*)d_in[7];
    const float* l3  = (const float*)d_in[8];
    float* out = (float*)d_out;

    const int n = out_size;                       // 500000

    if (ws_size >= 409600) {
        char* wsb = (char*)d_ws;
        hipLaunchKernelGGL(prescale_kernel, dim3(400), dim3(256), 0, stream,
                           c0, l0, c1, l1, c2, l2, c3, l3, wsb);
        const int waves  = (n + 63) / 64;         // 7813
        const int blocks = (waves + 3) / 4;       // 1954
        hipLaunchKernelGGL(mfma_chain, dim3(blocks), dim3(256), 0, stream,
                           idx, wsb, out, n);
    } else {
        const int grid = (n + 63) / 64;
        hipLaunchKernelGGL(chain_kernel_fb, dim3(grid), dim3(256), 0, stream,
                           idx, c0, l0, c1, l1, c2, l2, c3, l3, out, n);
    }
}

// Round 14
// 71.946 us; speedup vs baseline: 1.0049x; 1.0049x over previous
//
#include <hip/hip_runtime.h>

// BayesTensorRing via MFMA: out[s] = trace(M0'·M1'·M2'·M3'), Md' = core_d[idx_d]·diag(lam_d).
// ranks 16, dims 200, N = 500000. One sample = one wave-step; 64 samples per wave.
//
// trace = sum_{m,n} X[m][n]*Z[m][n]:  X = mfma(A=W0,B=W1^T) = M0'M1',
// Z = mfma(A=W3^T,B=W2) = (M2'M3')^T — two INDEPENDENT MFMAs, same D-layout slot,
// per-lane 4-term dot + 6-step DPP funnel -> lane 63.
//
// R14 key change: ws slices are stored in FRAGMENT ORDER — element consumed by
// (lane l, reg i) sits at slice position l*4+i. The per-sample gathers become
// fully contiguous 512B reads (voff = lane*8): 8 cache-line touches per load
// instr instead of ~32 with the old interleaved hoff pattern. R9-R13 flatness
// (~72us across 3 structures) diagnosed as L1/TA line-access bound.
//
// ws: W0p @0 | W1p(^T) @102400 | W2p @204800 | W3p(^T) @307200 (all f16, permuted).

typedef _Float16 f16x4 __attribute__((ext_vector_type(4)));
typedef _Float16 f16x2 __attribute__((ext_vector_type(2)));
typedef float    f32x4 __attribute__((ext_vector_type(4)));

#define DEV static __device__ __forceinline__

template<int CTRL>
DEV float dppmov(float x)
{
    return __int_as_float(__builtin_amdgcn_update_dpp(
        0, __float_as_int(x), CTRL, 0xF, 0xF, true));
}

// pinned 8B load: SGPR base + VGPR byte offset (saddr form)
DEV f16x4 ldg8s(const _Float16* sbase, int voff)
{
    f16x4 d;
    asm volatile("global_load_dwordx2 %0, %1, %2"
                 : "=&v"(d) : "v"(voff), "s"(sbase) : "memory");
    return d;
}

#define WAITV(N) asm volatile("s_waitcnt vmcnt(" #N ")" ::: "memory")

__global__ __launch_bounds__(256)
void mfma_chain(const int* __restrict__ idx, const char* __restrict__ wsb,
                float* __restrict__ out, int n)
{
    const _Float16* W0 = (const _Float16*)(wsb);
    const _Float16* W1 = (const _Float16*)(wsb + 102400);
    const _Float16* W2 = (const _Float16*)(wsb + 204800);
    const _Float16* W3 = (const _Float16*)(wsb + 307200);

    const int lane = threadIdx.x & 63;
    const int wv   = (blockIdx.x << 2) | (threadIdx.x >> 6);
    const int s0   = __builtin_amdgcn_readfirstlane(wv << 6);   // uniform wave base
    if (s0 >= n) return;
    const int cnt  = (n - s0 < 64) ? (n - s0) : 64;             // 64 or 32 here

    // fragment-order storage: lane l's 4 elements at slice bytes l*8 .. l*8+7
    const int voff = lane << 3;

    // preload this wave's 64 idx rows: lane l holds sample s0+min(l,cnt-1)
    const int lc = lane < cnt ? lane : cnt - 1;
    const int4 vidx = *(const int4*)(idx + 4l * (s0 + lc));

    float res = 0.f;

    #define ISSUE(S, t) {                                                   \
        const int tt = (t) < 63 ? (t) : 63;                                 \
        const int i0 = __builtin_amdgcn_readlane(vidx.x, tt);               \
        const int i1 = __builtin_amdgcn_readlane(vidx.y, tt);               \
        const int i2 = __builtin_amdgcn_readlane(vidx.z, tt);               \
        const int i3 = __builtin_amdgcn_readlane(vidx.w, tt);               \
        S##a0 = ldg8s(W0 + i0 * 256, voff);                                 \
        S##b1 = ldg8s(W1 + i1 * 256, voff);                                 \
        S##b2 = ldg8s(W2 + i2 * 256, voff);                                 \
        S##a3 = ldg8s(W3 + i3 * 256, voff);                                 \
    }

    #define COMP(S, t) {                                                    \
        WAITV(12);                                                          \
        __builtin_amdgcn_sched_barrier(0);                                  \
        const f32x4 z = {0.f, 0.f, 0.f, 0.f};                               \
        f32x4 X = __builtin_amdgcn_mfma_f32_16x16x16f16(S##a0, S##b1, z, 0, 0, 0); \
        f32x4 Z = __builtin_amdgcn_mfma_f32_16x16x16f16(S##a3, S##b2, z, 0, 0, 0); \
        float p =       X[0] * Z[0];                                        \
        p = fmaf(X[1], Z[1], p);                                            \
        p = fmaf(X[2], Z[2], p);                                            \
        p = fmaf(X[3], Z[3], p);                                            \
        p += dppmov<0x111>(p);                                              \
        p += dppmov<0x112>(p);                                              \
        p += dppmov<0x114>(p);                                              \
        p += dppmov<0x118>(p);                                              \
        p += dppmov<0x142>(p);                                              \
        p += dppmov<0x143>(p);                                              \
        const int pv = __builtin_amdgcn_readlane(__float_as_int(p), 63);    \
        res = (lane == (t)) ? __int_as_float(pv) : res;                     \
    }

    f16x4 Aa0, Ab1, Ab2, Aa3;
    f16x4 Ba0, Bb1, Bb2, Ba3;
    f16x4 Ca0, Cb1, Cb2, Ca3;
    f16x4 Da0, Db1, Db2, Da3;

    ISSUE(A, 0); ISSUE(B, 1); ISSUE(C, 2); ISSUE(D, 3);

    const int cntR = (cnt + 3) & ~3;     // 64 or 32
    for (int t = 0; t + 4 <= cntR; t += 4) {
        COMP(A, t);     ISSUE(A, t + 4);
        COMP(B, t + 1); ISSUE(B, t + 5);
        COMP(C, t + 2); ISSUE(C, t + 6);
        COMP(D, t + 3); ISSUE(D, t + 7);
    }

    if (lane < cnt) out[s0 + lane] = res;   // one coalesced store per wave

    #undef ISSUE
    #undef COMP
}

// fragment-order permutation: old slice position p -> lane l = (p>>4) + 16*((p&15)>>2),
// new position 4*l + (p&3). f16x2 pairs (p even in last 2 bits' quad) stay contiguous.
DEV int permpos(int p)
{
    const int l = (p >> 4) + (((p & 15) >> 2) << 4);
    return (l << 2) + (p & 3);
}

// Prescale + reformat cores into ws (f16, fragment-order): W0 rm, W1^T, W2 rm, W3^T.
__global__ __launch_bounds__(256)
void prescale_kernel(const float* __restrict__ cr0, const float* __restrict__ lm0,
                     const float* __restrict__ cr1, const float* __restrict__ lm1,
                     const float* __restrict__ cr2, const float* __restrict__ lm2,
                     const float* __restrict__ cr3, const float* __restrict__ lm3,
                     char* __restrict__ wsb)
{
    _Float16* W0 = (_Float16*)(wsb);
    _Float16* W1 = (_Float16*)(wsb + 102400);
    _Float16* W2 = (_Float16*)(wsb + 204800);
    _Float16* W3 = (_Float16*)(wsb + 307200);

    const int bx  = blockIdx.x;          // 0..399
    const int d   = bx / 100;            // matrix id (uniform per block)
    const int gid = (bx % 100) * 256 + threadIdx.x;   // 0..25599
    const int i   = gid >> 7;            // slice 0..199
    const int pr  = gid & 127;           // pair id 0..127

    if (d == 0 || d == 2) {
        const float* cp = (d == 0) ? cr0 : cr2;
        const float* lp = (d == 0) ? lm0 : lm2;
        _Float16*    Wt = (d == 0) ? W0 : W2;
        const int r = pr >> 3, c = (pr & 7) * 2;      // row-major logical pos
        const float2 v = *(const float2*)(cp + i * 256 + r * 16 + c);
        f16x2 o; o[0] = (_Float16)(v.x * lp[c]); o[1] = (_Float16)(v.y * lp[c + 1]);
        *(f16x2*)(Wt + i * 256 + permpos(r * 16 + c)) = o;
    } else {
        const float* cp = (d == 1) ? cr1 : cr3;
        const float* lp = (d == 1) ? lm1 : lm3;
        _Float16*    Wt = (d == 1) ? W1 : W3;
        const int c = pr >> 3, r = (pr & 7) * 2;      // transposed logical pos c*16+r
        const float a = cp[i * 256 + r * 16 + c]       * lp[c];
        const float b = cp[i * 256 + (r + 1) * 16 + c] * lp[c];
        f16x2 o; o[0] = (_Float16)a; o[1] = (_Float16)b;
        *(f16x2*)(Wt + i * 256 + permpos(c * 16 + r)) = o;
    }
}

// ---------------- fallback (no workspace): R5 DPP vector kernel ----------------
template<int CTRL>
DEV float dppf(float x)
{
    return __int_as_float(__builtin_amdgcn_update_dpp(
        0, __float_as_int(x), CTRL, 0xF, 0xF, true));
}

DEV void mm16g_lam(const float (&a)[4][16], float (&b)[4][16],
                   const float* __restrict__ m, const float* __restrict__ lam)
{
    const float4* m4 = reinterpret_cast<const float4*>(m);
    float4 lv[4];
#pragma unroll
    for (int q = 0; q < 4; ++q) lv[q] = reinterpret_cast<const float4*>(lam)[q];
#pragma unroll
    for (int nn = 0; nn < 16; ++nn) {
        float mrow[16];
#pragma unroll
        for (int q = 0; q < 4; ++q) {
            float4 v = m4[4 * nn + q];
            v.x *= lv[q].x; v.y *= lv[q].y; v.z *= lv[q].z; v.w *= lv[q].w;
            mrow[4*q+0] = v.x; mrow[4*q+1] = v.y;
            mrow[4*q+2] = v.z; mrow[4*q+3] = v.w;
        }
#pragma unroll
        for (int r = 0; r < 4; ++r) {
            const float av = a[r][nn];
            if (nn == 0) {
#pragma unroll
                for (int k = 0; k < 16; ++k) b[r][k] = av * mrow[k];
            } else {
#pragma unroll
                for (int k = 0; k < 16; ++k) b[r][k] = fmaf(av, mrow[k], b[r][k]);
            }
        }
    }
}

__global__ __launch_bounds__(256)
void chain_kernel_fb(const int* __restrict__ idx,
                     const float* __restrict__ c0, const float* __restrict__ l0,
                     const float* __restrict__ c1, const float* __restrict__ l1,
                     const float* __restrict__ c2, const float* __restrict__ l2,
                     const float* __restrict__ c3, const float* __restrict__ l3,
                     float* __restrict__ out, int n)
{
    const int tid  = threadIdx.x;
    const int slot = tid >> 2;
    const int j    = tid & 3;
    const int s    = blockIdx.x * 64 + slot;
    const int sc   = s < n ? s : n - 1;

    const int4 ix = *reinterpret_cast<const int4*>(idx + 4l * sc);

    float a[4][16], b[4][16];
    {
        const float4* src = reinterpret_cast<const float4*>(c0 + 256l * ix.x) + 16 * j;
#pragma unroll
        for (int t = 0; t < 16; ++t) {
            float4 v = src[t];
            const float4 L = reinterpret_cast<const float4*>(l0)[t & 3];
            const int r = t >> 2, c = (t & 3) * 4;
            a[r][c+0] = v.x * L.x; a[r][c+1] = v.y * L.y;
            a[r][c+2] = v.z * L.z; a[r][c+3] = v.w * L.w;
        }
    }

    mm16g_lam(a, b, c1 + 256l * ix.y, l1);
    mm16g_lam(b, a, c2 + 256l * ix.z, l2);

    float4 part = make_float4(0.f, 0.f, 0.f, 0.f);
    const float* base3 = c3 + 256l * ix.w + 4 * j;
#pragma unroll
    for (int nn = 0; nn < 16; ++nn) {
        const float4 v = *reinterpret_cast<const float4*>(base3 + 16 * nn);
        part.x = fmaf(a[0][nn], v.x, part.x);
        part.y = fmaf(a[1][nn], v.y, part.y);
        part.z = fmaf(a[2][nn], v.z, part.z);
        part.w = fmaf(a[3][nn], v.w, part.w);
    }
    const float4 L3 = reinterpret_cast<const float4*>(l3)[j];
    float p = part.x * L3.x + part.y * L3.y + part.z * L3.z + part.w * L3.w;

    p += __shfl_xor(p, 1);
    p += __shfl_xor(p, 2);

    if (s < n && j == 0) out[s] = p;
}

extern "C" void kernel_launch(void* const* d_in, const int* in_sizes, int n_in,
                              void* d_out, int out_size, void* d_ws, size_t ws_size,
                              hipStream_t stream)
{
    const int*   idx = (const int*)  d_in[0];
    const float* c0  = (const float*)d_in[1];
    const float* l0  = (const float*)d_in[2];
    const float* c1  = (const float*)d_in[3];
    const float* l1  = (const float*)d_in[4];
    const float* c2  = (const float*)d_in[5];
    const float* l2  = (const float*)d_in[6];
    const float* c3  = (const float*)d_in[7];
    const float* l3  = (const float*)d_in[8];
    float* out = (float*)d_out;

    const int n = out_size;                       // 500000

    if (ws_size >= 409600) {
        char* wsb = (char*)d_ws;
        hipLaunchKernelGGL(prescale_kernel, dim3(400), dim3(256), 0, stream,
                           c0, l0, c1, l1, c2, l2, c3, l3, wsb);
        const int waves  = (n + 63) / 64;         // 7813
        const int blocks = (waves + 3) / 4;       // 1954
        hipLaunchKernelGGL(mfma_chain, dim3(blocks), dim3(256), 0, stream,
                           idx, wsb, out, n);
    } else {
        const int grid = (n + 63) / 64;
        hipLaunchKernelGGL(chain_kernel_fb, dim3(grid), dim3(256), 0, stream,
                           idx, c0, l0, c1, l1, c2, l2, c3, l3, out, n);
    }
}

// Round 15
// 55.656 us; speedup vs baseline: 1.2990x; 1.2927x over previous
//
#include <hip/hip_runtime.h>

// BayesTensorRing via paired 32x32x16 MFMA: out[s]=trace(M0'M1'M2'M3').
// TWO samples per MFMA pair: X^=mfma(A=[M0s;M0s'],B=[M1s|M1s']) -> diag blocks
// X_s, X_s'; Z^ likewise with A=[M3'^T pair], B=[M2'^T-content pair] -> diag
// (M2'M3')^T. trace_s = sum over diag-block entries X*Z. Each operand pair is
// ONE dwordx4/lane load (1KB/wave) -> 4 VMEM inst per 2 samples (was 8).
// R9-R14 flat at ~72us across all latency structures -> testing VMEM-inst-rate
// hypothesis (TA ~16cyc/wave-inst) vs byte-throughput (then flat).
//
// Fragment assumption (gfx950 2xK = stacked 32x32x8): A[row=l&31][k=8j+4(l>>5)+i],
// B[col=l&31][k same]; C/D verified: col=l&31, row=(reg&3)+8(reg>>2)+4(l>>5).
// ws granule order: lane l reads 16B at slice byte ((l>>5)*16+(l&15))*16; slice
// sel by lane bit4. W0/W2 row-major-form (lam over k), W1/W3 transpose-form
// (lam over q) — orientation matches R13's verified hoff semantics.
// ws: W0@0 | W1@102400 | W2@204800 | W3@307200 (f16, 512B slices). 409600B.

typedef _Float16 f16x8  __attribute__((ext_vector_type(8)));
typedef _Float16 f16x2  __attribute__((ext_vector_type(2)));
typedef float    f32x16 __attribute__((ext_vector_type(16)));

#define DEV static __device__ __forceinline__

template<int CTRL>
DEV float dppmov(float x)
{
    return __int_as_float(__builtin_amdgcn_update_dpp(
        0, __float_as_int(x), CTRL, 0xF, 0xF, true));
}

// pinned 16B load: SGPR base + VGPR byte offset
DEV f16x8 ldg16s(const _Float16* sbase, int voff)
{
    f16x8 d;
    asm volatile("global_load_dwordx4 %0, %1, %2"
                 : "=&v"(d) : "v"(voff), "s"(sbase) : "memory");
    return d;
}

#define WAITV(N) asm volatile("s_waitcnt vmcnt(" #N ")" ::: "memory")
#define RL(v, l) __builtin_amdgcn_readlane((v), (l))

__global__ __launch_bounds__(256)
void mfma_chain(const int* __restrict__ idx, const char* __restrict__ wsb,
                float* __restrict__ out, int n)
{
    const _Float16* W0 = (const _Float16*)(wsb);
    const _Float16* W1 = (const _Float16*)(wsb + 102400);
    const _Float16* W2 = (const _Float16*)(wsb + 204800);
    const _Float16* W3 = (const _Float16*)(wsb + 307200);

    const int lane = threadIdx.x & 63;
    const int wv   = (blockIdx.x << 2) | (threadIdx.x >> 6);
    const int s0   = __builtin_amdgcn_readfirstlane(wv << 6);
    if (s0 >= n) return;
    const int cnt  = (n - s0 < 64) ? (n - s0) : 64;             // 64 or 32

    // per-lane in-slice byte offset (granule (l>>5)*16 + (l&15), 16B each)
    const int voff = ((lane >> 5) << 8) + ((lane & 15) << 4);
    const bool hi   = (lane >> 4) & 1;      // this lane serves sample t+1
    const bool clow = (lane & 31) < 16;     // C col < 16 -> sample t's diag block

    const int lc = lane < cnt ? lane : cnt - 1;
    const int4 vidx = *(const int4*)(idx + 4l * (s0 + lc));

    float res = 0.f;

    #define ISSUE(S, t) {                                                    \
        const int ta = (t) < 63 ? (t) : 63;                                  \
        const int tb = (t) + 1 < 63 ? (t) + 1 : 63;                          \
        const int i0a = RL(vidx.x, ta), i0b = RL(vidx.x, tb);                \
        const int i1a = RL(vidx.y, ta), i1b = RL(vidx.y, tb);                \
        const int i2a = RL(vidx.z, ta), i2b = RL(vidx.z, tb);                \
        const int i3a = RL(vidx.w, ta), i3b = RL(vidx.w, tb);                \
        S##a0 = ldg16s(W0, ((hi ? i0b : i0a) << 9) + voff);                  \
        S##b1 = ldg16s(W1, ((hi ? i1b : i1a) << 9) + voff);                  \
        S##b2 = ldg16s(W2, ((hi ? i2b : i2a) << 9) + voff);                  \
        S##a3 = ldg16s(W3, ((hi ? i3b : i3a) << 9) + voff);                  \
    }

    #define COMP(S, t) {                                                     \
        WAITV(12);                                                           \
        __builtin_amdgcn_sched_barrier(0);                                   \
        const f32x16 z = {};                                                 \
        f32x16 X = __builtin_amdgcn_mfma_f32_32x32x16_f16(S##a0, S##b1, z, 0, 0, 0); \
        f32x16 Z = __builtin_amdgcn_mfma_f32_32x32x16_f16(S##a3, S##b2, z, 0, 0, 0); \
        float dlo =      X[0] * Z[0];                                        \
        dlo = fmaf(X[1], Z[1], dlo); dlo = fmaf(X[2], Z[2], dlo);            \
        dlo = fmaf(X[3], Z[3], dlo); dlo = fmaf(X[4], Z[4], dlo);            \
        dlo = fmaf(X[5], Z[5], dlo); dlo = fmaf(X[6], Z[6], dlo);            \
        dlo = fmaf(X[7], Z[7], dlo);                                         \
        float dhi =      X[8] * Z[8];                                        \
        dhi = fmaf(X[9],  Z[9],  dhi); dhi = fmaf(X[10], Z[10], dhi);        \
        dhi = fmaf(X[11], Z[11], dhi); dhi = fmaf(X[12], Z[12], dhi);        \
        dhi = fmaf(X[13], Z[13], dhi); dhi = fmaf(X[14], Z[14], dhi);        \
        dhi = fmaf(X[15], Z[15], dhi);                                       \
        float p = clow ? dlo : dhi;                                          \
        p += dppmov<0x111>(p);                                               \
        p += dppmov<0x112>(p);                                               \
        p += dppmov<0x114>(p);                                               \
        p += dppmov<0x118>(p);                                               \
        p += __shfl_xor(p, 32);                                              \
        const int pa = RL(__float_as_int(p), 15);                            \
        const int pb = RL(__float_as_int(p), 31);                            \
        res = (lane == (t))     ? __int_as_float(pa) : res;                  \
        res = (lane == (t) + 1) ? __int_as_float(pb) : res;                  \
    }

    f16x8 Aa0, Ab1, Ab2, Aa3;
    f16x8 Ba0, Bb1, Bb2, Ba3;
    f16x8 Ca0, Cb1, Cb2, Ca3;
    f16x8 Da0, Db1, Db2, Da3;

    ISSUE(A, 0); ISSUE(B, 2); ISSUE(C, 4); ISSUE(D, 6);

    const int cntR = (cnt + 7) & ~7;     // 64 or 32
    for (int t = 0; t + 8 <= cntR; t += 8) {
        COMP(A, t);     ISSUE(A, t + 8);
        COMP(B, t + 2); ISSUE(B, t + 10);
        COMP(C, t + 4); ISSUE(C, t + 12);
        COMP(D, t + 6); ISSUE(D, t + 14);
    }

    if (lane < cnt) out[s0 + lane] = res;

    #undef ISSUE
    #undef COMP
}

// Prescale into granule order. pair pr in 0..127: g=pr>>2, w=pr&3; h=g>>4, q=g&15;
// k0 = 8*(w>>1) + 4*h + 2*(w&1); store at slice pos g*8 + 2w.
// W0/W2 (row-major form): elems M[q][k0..k0+1] * lam[k0..k0+1]
// W1/W3 (transpose form): elems M[k0][q], M[k0+1][q] * lam[q]
__global__ __launch_bounds__(256)
void prescale_kernel(const float* __restrict__ cr0, const float* __restrict__ lm0,
                     const float* __restrict__ cr1, const float* __restrict__ lm1,
                     const float* __restrict__ cr2, const float* __restrict__ lm2,
                     const float* __restrict__ cr3, const float* __restrict__ lm3,
                     char* __restrict__ wsb)
{
    _Float16* W0 = (_Float16*)(wsb);
    _Float16* W1 = (_Float16*)(wsb + 102400);
    _Float16* W2 = (_Float16*)(wsb + 204800);
    _Float16* W3 = (_Float16*)(wsb + 307200);

    const int bx  = blockIdx.x;          // 0..399
    const int d   = bx / 100;            // table id (uniform per block)
    const int gid = (bx % 100) * 256 + threadIdx.x;   // 0..25599
    const int i   = gid >> 7;            // slice 0..199
    const int pr  = gid & 127;           // pair 0..127

    const int g  = pr >> 2, w = pr & 3;
    const int h  = g >> 4,  q = g & 15;
    const int k0 = 8 * (w >> 1) + 4 * h + 2 * (w & 1);
    const int dstpos = i * 256 + g * 8 + 2 * w;

    if (d == 0 || d == 2) {
        const float* cp = (d == 0) ? cr0 : cr2;
        const float* lp = (d == 0) ? lm0 : lm2;
        _Float16*    Wt = (d == 0) ? W0 : W2;
        const float2 v = *(const float2*)(cp + i * 256 + q * 16 + k0);
        f16x2 o; o[0] = (_Float16)(v.x * lp[k0]); o[1] = (_Float16)(v.y * lp[k0 + 1]);
        *(f16x2*)(Wt + dstpos) = o;
    } else {
        const float* cp = (d == 1) ? cr1 : cr3;
        const float* lp = (d == 1) ? lm1 : lm3;
        _Float16*    Wt = (d == 1) ? W1 : W3;
        const float a = cp[i * 256 + k0 * 16 + q]       * lp[q];
        const float b = cp[i * 256 + (k0 + 1) * 16 + q] * lp[q];
        f16x2 o; o[0] = (_Float16)a; o[1] = (_Float16)b;
        *(f16x2*)(Wt + dstpos) = o;
    }
}

// ---------------- fallback (no workspace): R5 DPP vector kernel ----------------
template<int CTRL>
DEV float dppf(float x)
{
    return __int_as_float(__builtin_amdgcn_update_dpp(
        0, __float_as_int(x), CTRL, 0xF, 0xF, true));
}

DEV void mm16g_lam(const float (&a)[4][16], float (&b)[4][16],
                   const float* __restrict__ m, const float* __restrict__ lam)
{
    const float4* m4 = reinterpret_cast<const float4*>(m);
    float4 lv[4];
#pragma unroll
    for (int q = 0; q < 4; ++q) lv[q] = reinterpret_cast<const float4*>(lam)[q];
#pragma unroll
    for (int nn = 0; nn < 16; ++nn) {
        float mrow[16];
#pragma unroll
        for (int q = 0; q < 4; ++q) {
            float4 v = m4[4 * nn + q];
            v.x *= lv[q].x; v.y *= lv[q].y; v.z *= lv[q].z; v.w *= lv[q].w;
            mrow[4*q+0] = v.x; mrow[4*q+1] = v.y;
            mrow[4*q+2] = v.z; mrow[4*q+3] = v.w;
        }
#pragma unroll
        for (int r = 0; r < 4; ++r) {
            const float av = a[r][nn];
            if (nn == 0) {
#pragma unroll
                for (int k = 0; k < 16; ++k) b[r][k] = av * mrow[k];
            } else {
#pragma unroll
                for (int k = 0; k < 16; ++k) b[r][k] = fmaf(av, mrow[k], b[r][k]);
            }
        }
    }
}

__global__ __launch_bounds__(256)
void chain_kernel_fb(const int* __restrict__ idx,
                     const float* __restrict__ c0, const float* __restrict__ l0,
                     const float* __restrict__ c1, const float* __restrict__ l1,
                     const float* __restrict__ c2, const float* __restrict__ l2,
                     const float* __restrict__ c3, const float* __restrict__ l3,
                     float* __restrict__ out, int n)
{
    const int tid  = threadIdx.x;
    const int slot = tid >> 2;
    const int j    = tid & 3;
    const int s    = blockIdx.x * 64 + slot;
    const int sc   = s < n ? s : n - 1;

    const int4 ix = *reinterpret_cast<const int4*>(idx + 4l * sc);

    float a[4][16], b[4][16];
    {
        const float4* src = reinterpret_cast<const float4*>(c0 + 256l * ix.x) + 16 * j;
#pragma unroll
        for (int t = 0; t < 16; ++t) {
            float4 v = src[t];
            const float4 L = reinterpret_cast<const float4*>(l0)[t & 3];
            const int r = t >> 2, c = (t & 3) * 4;
            a[r][c+0] = v.x * L.x; a[r][c+1] = v.y * L.y;
            a[r][c+2] = v.z * L.z; a[r][c+3] = v.w * L.w;
        }
    }

    mm16g_lam(a, b, c1 + 256l * ix.y, l1);
    mm16g_lam(b, a, c2 + 256l * ix.z, l2);

    float4 part = make_float4(0.f, 0.f, 0.f, 0.f);
    const float* base3 = c3 + 256l * ix.w + 4 * j;
#pragma unroll
    for (int nn = 0; nn < 16; ++nn) {
        const float4 v = *reinterpret_cast<const float4*>(base3 + 16 * nn);
        part.x = fmaf(a[0][nn], v.x, part.x);
        part.y = fmaf(a[1][nn], v.y, part.y);
        part.z = fmaf(a[2][nn], v.z, part.z);
        part.w = fmaf(a[3][nn], v.w, part.w);
    }
    const float4 L3 = reinterpret_cast<const float4*>(l3)[j];
    float p = part.x * L3.x + part.y * L3.y + part.z * L3.z + part.w * L3.w;

    p += __shfl_xor(p, 1);
    p += __shfl_xor(p, 2);

    if (s < n && j == 0) out[s] = p;
}

extern "C" void kernel_launch(void* const* d_in, const int* in_sizes, int n_in,
                              void* d_out, int out_size, void* d_ws, size_t ws_size,
                              hipStream_t stream)
{
    const int*   idx = (const int*)  d_in[0];
    const float* c0  = (const float*)d_in[1];
    const float* l0  = (const float*)d_in[2];
    const float* c1  = (const float*)d_in[3];
    const float* l1  = (const float*)d_in[4];
    const float* c2  = (const float*)d_in[5];
    const float* l2  = (const float*)d_in[6];
    const float* c3  = (const float*)d_in[7];
    const float* l3  = (const float*)d_in[8];
    float* out = (float*)d_out;

    const int n = out_size;                       // 500000

    if (ws_size >= 409600) {
        char* wsb = (char*)d_ws;
        hipLaunchKernelGGL(prescale_kernel, dim3(400), dim3(256), 0, stream,
                           c0, l0, c1, l1, c2, l2, c3, l3, wsb);
        const int waves  = (n + 63) / 64;         // 7813
        const int blocks = (waves + 3) / 4;       // 1954
        hipLaunchKernelGGL(mfma_chain, dim3(blocks), dim3(256), 0, stream,
                           idx, wsb, out, n);
    } else {
        const int grid = (n + 63) / 64;
        hipLaunchKernelGGL(chain_kernel_fb, dim3(grid), dim3(256), 0, stream,
                           idx, c0, l0, c1, l1, c2, l2, c3, l3, out, n);
    }
}

// Round 16
// 55.230 us; speedup vs baseline: 1.3091x; 1.0077x over previous
//
#include <hip/hip_runtime.h>

// BayesTensorRing via paired 32x32x16 MFMA: out[s]=trace(M0'M1'M2'M3').
// Two samples per MFMA pair (diag blocks); trace = per-lane pk-dot of X,Z diag
// entries + DPP funnel. R15 proved VMEM-inst halving (72->54us); now VALU-bound
// (75% busy). R16 cuts VALU: __shfl(ds_bpermute, LDS pipe) index distribution
// (replaces 8 readlane + 4 cndmask), v_pk_fma_f32 packed dot (16 FMA -> 8 pk),
// hoisted zero accumulator.
//
// Layouts (verified by R15 pass): A[row=l&31][k=8j+4(l>>5)+i], B[col same],
// C/D: col=l&31, row=(reg&3)+8(reg>>2)+4(l>>5). ws granule order: lane reads
// 16B at slice byte ((l>>5)*16+(l&15))*16, slice select by lane bit4.
// ws: W0@0 | W1@102400 | W2@204800 | W3@307200 (f16, 512B slices). 409600B.

typedef _Float16 f16x8  __attribute__((ext_vector_type(8)));
typedef _Float16 f16x2  __attribute__((ext_vector_type(2)));
typedef float    f32x16 __attribute__((ext_vector_type(16)));
typedef float    f32x2  __attribute__((ext_vector_type(2)));

#define DEV static __device__ __forceinline__

template<int CTRL>
DEV float dppmov(float x)
{
    return __int_as_float(__builtin_amdgcn_update_dpp(
        0, __float_as_int(x), CTRL, 0xF, 0xF, true));
}

DEV f16x8 ldg16s(const _Float16* sbase, int voff)
{
    f16x8 d;
    asm volatile("global_load_dwordx4 %0, %1, %2"
                 : "=&v"(d) : "v"(voff), "s"(sbase) : "memory");
    return d;
}

DEV f32x2 pkfma(f32x2 a, f32x2 b, f32x2 c)
{
    f32x2 d;
    asm("v_pk_fma_f32 %0, %1, %2, %3" : "=v"(d) : "v"(a), "v"(b), "v"(c));
    return d;
}

#define WAITV(N) asm volatile("s_waitcnt vmcnt(" #N ")" ::: "memory")
#define RL(v, l) __builtin_amdgcn_readlane((v), (l))

union Acc16 { f32x16 v; f32x2 p[8]; };

__global__ __launch_bounds__(256)
void mfma_chain(const int* __restrict__ idx, const char* __restrict__ wsb,
                float* __restrict__ out, int n)
{
    const _Float16* W0 = (const _Float16*)(wsb);
    const _Float16* W1 = (const _Float16*)(wsb + 102400);
    const _Float16* W2 = (const _Float16*)(wsb + 204800);
    const _Float16* W3 = (const _Float16*)(wsb + 307200);

    const int lane = threadIdx.x & 63;
    const int wv   = (blockIdx.x << 2) | (threadIdx.x >> 6);
    const int s0   = __builtin_amdgcn_readfirstlane(wv << 6);
    if (s0 >= n) return;
    const int cnt  = (n - s0 < 64) ? (n - s0) : 64;             // 64 or 32

    const int voff = ((lane >> 5) << 8) + ((lane & 15) << 4);   // in-slice byte off
    const int hiI  = (lane >> 4) & 1;       // serves sample t+1
    const bool clow = (lane & 31) < 16;     // col<16 -> sample t diag block

    const int lc = lane < cnt ? lane : cnt - 1;
    const int4 vidx = *(const int4*)(idx + 4l * (s0 + lc));
    // pre-shifted slice byte offsets (slice i at byte i*512)
    const int vo0 = (vidx.x << 9), vo1 = (vidx.y << 9);
    const int vo2 = (vidx.z << 9), vo3 = (vidx.w << 9);

    float res = 0.f;
    const f32x16 zacc = {};   // hoisted zero accumulator

    // issue pair (t, t+1): per-lane source lane t|hi via ds_bpermute (LDS pipe)
    #define ISSUE(S, t) {                                                    \
        const int tb   = (t) <= 62 ? (t) : 62;                               \
        const int tsel = tb | hiI;                                           \
        S##a0 = ldg16s(W0, __shfl(vo0, tsel) + voff);                        \
        S##b1 = ldg16s(W1, __shfl(vo1, tsel) + voff);                        \
        S##b2 = ldg16s(W2, __shfl(vo2, tsel) + voff);                        \
        S##a3 = ldg16s(W3, __shfl(vo3, tsel) + voff);                        \
    }

    #define COMP(S, t) {                                                     \
        WAITV(12);                                                           \
        __builtin_amdgcn_sched_barrier(0);                                   \
        Acc16 X, Z;                                                          \
        X.v = __builtin_amdgcn_mfma_f32_32x32x16_f16(S##a0, S##b1, zacc, 0, 0, 0); \
        Z.v = __builtin_amdgcn_mfma_f32_32x32x16_f16(S##a3, S##b2, zacc, 0, 0, 0); \
        f32x2 zero2 = {0.f, 0.f};                                            \
        f32x2 dlo = pkfma(X.p[0], Z.p[0], zero2);                            \
        dlo = pkfma(X.p[1], Z.p[1], dlo);                                    \
        dlo = pkfma(X.p[2], Z.p[2], dlo);                                    \
        dlo = pkfma(X.p[3], Z.p[3], dlo);                                    \
        f32x2 dhi = pkfma(X.p[4], Z.p[4], zero2);                            \
        dhi = pkfma(X.p[5], Z.p[5], dhi);                                    \
        dhi = pkfma(X.p[6], Z.p[6], dhi);                                    \
        dhi = pkfma(X.p[7], Z.p[7], dhi);                                    \
        const float s0f = clow ? dlo[0] : dhi[0];                            \
        const float s1f = clow ? dlo[1] : dhi[1];                            \
        float p = s0f + s1f;                                                 \
        p += dppmov<0x111>(p);                                               \
        p += dppmov<0x112>(p);                                               \
        p += dppmov<0x114>(p);                                               \
        p += dppmov<0x118>(p);                                               \
        p += __shfl_xor(p, 32);                                              \
        const int pa = RL(__float_as_int(p), 15);                            \
        const int pb = RL(__float_as_int(p), 31);                            \
        res = (lane == (t))     ? __int_as_float(pa) : res;                  \
        res = (lane == (t) + 1) ? __int_as_float(pb) : res;                  \
    }

    f16x8 Aa0, Ab1, Ab2, Aa3;
    f16x8 Ba0, Bb1, Bb2, Ba3;
    f16x8 Ca0, Cb1, Cb2, Ca3;
    f16x8 Da0, Db1, Db2, Da3;

    ISSUE(A, 0); ISSUE(B, 2); ISSUE(C, 4); ISSUE(D, 6);

    const int cntR = (cnt + 7) & ~7;     // 64 or 32
    for (int t = 0; t + 8 <= cntR; t += 8) {
        COMP(A, t);     ISSUE(A, t + 8);
        COMP(B, t + 2); ISSUE(B, t + 10);
        COMP(C, t + 4); ISSUE(C, t + 12);
        COMP(D, t + 6); ISSUE(D, t + 14);
    }

    if (lane < cnt) out[s0 + lane] = res;

    #undef ISSUE
    #undef COMP
}

// Prescale into granule order (same as R15, verified). pr: g=pr>>2, w=pr&3;
// h=g>>4, q=g&15; k0=8*(w>>1)+4*h+2*(w&1); dst slice pos g*8+2w.
__global__ __launch_bounds__(256)
void prescale_kernel(const float* __restrict__ cr0, const float* __restrict__ lm0,
                     const float* __restrict__ cr1, const float* __restrict__ lm1,
                     const float* __restrict__ cr2, const float* __restrict__ lm2,
                     const float* __restrict__ cr3, const float* __restrict__ lm3,
                     char* __restrict__ wsb)
{
    _Float16* W0 = (_Float16*)(wsb);
    _Float16* W1 = (_Float16*)(wsb + 102400);
    _Float16* W2 = (_Float16*)(wsb + 204800);
    _Float16* W3 = (_Float16*)(wsb + 307200);

    const int bx  = blockIdx.x;
    const int d   = bx / 100;
    const int gid = (bx % 100) * 256 + threadIdx.x;
    const int i   = gid >> 7;
    const int pr  = gid & 127;

    const int g  = pr >> 2, w = pr & 3;
    const int h  = g >> 4,  q = g & 15;
    const int k0 = 8 * (w >> 1) + 4 * h + 2 * (w & 1);
    const int dstpos = i * 256 + g * 8 + 2 * w;

    if (d == 0 || d == 2) {
        const float* cp = (d == 0) ? cr0 : cr2;
        const float* lp = (d == 0) ? lm0 : lm2;
        _Float16*    Wt = (d == 0) ? W0 : W2;
        const float2 v = *(const float2*)(cp + i * 256 + q * 16 + k0);
        f16x2 o; o[0] = (_Float16)(v.x * lp[k0]); o[1] = (_Float16)(v.y * lp[k0 + 1]);
        *(f16x2*)(Wt + dstpos) = o;
    } else {
        const float* cp = (d == 1) ? cr1 : cr3;
        const float* lp = (d == 1) ? lm1 : lm3;
        _Float16*    Wt = (d == 1) ? W1 : W3;
        const float a = cp[i * 256 + k0 * 16 + q]       * lp[q];
        const float b = cp[i * 256 + (k0 + 1) * 16 + q] * lp[q];
        f16x2 o; o[0] = (_Float16)a; o[1] = (_Float16)b;
        *(f16x2*)(Wt + dstpos) = o;
    }
}

// ---------------- fallback (no workspace): R5 DPP vector kernel ----------------
template<int CTRL>
DEV float dppf(float x)
{
    return __int_as_float(__builtin_amdgcn_update_dpp(
        0, __float_as_int(x), CTRL, 0xF, 0xF, true));
}

DEV void mm16g_lam(const float (&a)[4][16], float (&b)[4][16],
                   const float* __restrict__ m, const float* __restrict__ lam)
{
    const float4* m4 = reinterpret_cast<const float4*>(m);
    float4 lv[4];
#pragma unroll
    for (int q = 0; q < 4; ++q) lv[q] = reinterpret_cast<const float4*>(lam)[q];
#pragma unroll
    for (int nn = 0; nn < 16; ++nn) {
        float mrow[16];
#pragma unroll
        for (int q = 0; q < 4; ++q) {
            float4 v = m4[4 * nn + q];
            v.x *= lv[q].x; v.y *= lv[q].y; v.z *= lv[q].z; v.w *= lv[q].w;
            mrow[4*q+0] = v.x; mrow[4*q+1] = v.y;
            mrow[4*q+2] = v.z; mrow[4*q+3] = v.w;
        }
#pragma unroll
        for (int r = 0; r < 4; ++r) {
            const float av = a[r][nn];
            if (nn == 0) {
#pragma unroll
                for (int k = 0; k < 16; ++k) b[r][k] = av * mrow[k];
            } else {
#pragma unroll
                for (int k = 0; k < 16; ++k) b[r][k] = fmaf(av, mrow[k], b[r][k]);
            }
        }
    }
}

__global__ __launch_bounds__(256)
void chain_kernel_fb(const int* __restrict__ idx,
                     const float* __restrict__ c0, const float* __restrict__ l0,
                     const float* __restrict__ c1, const float* __restrict__ l1,
                     const float* __restrict__ c2, const float* __restrict__ l2,
                     const float* __restrict__ c3, const float* __restrict__ l3,
                     float* __restrict__ out, int n)
{
    const int tid  = threadIdx.x;
    const int slot = tid >> 2;
    const int j    = tid & 3;
    const int s    = blockIdx.x * 64 + slot;
    const int sc   = s < n ? s : n - 1;

    const int4 ix = *reinterpret_cast<const int4*>(idx + 4l * sc);

    float a[4][16], b[4][16];
    {
        const float4* src = reinterpret_cast<const float4*>(c0 + 256l * ix.x) + 16 * j;
#pragma unroll
        for (int t = 0; t < 16; ++t) {
            float4 v = src[t];
            const float4 L = reinterpret_cast<const float4*>(l0)[t & 3];
            const int r = t >> 2, c = (t & 3) * 4;
            a[r][c+0] = v.x * L.x; a[r][c+1] = v.y * L.y;
            a[r][c+2] = v.z * L.z; a[r][c+3] = v.w * L.w;
        }
    }

    mm16g_lam(a, b, c1 + 256l * ix.y, l1);
    mm16g_lam(b, a, c2 + 256l * ix.z, l2);

    float4 part = make_float4(0.f, 0.f, 0.f, 0.f);
    const float* base3 = c3 + 256l * ix.w + 4 * j;
#pragma unroll
    for (int nn = 0; nn < 16; ++nn) {
        const float4 v = *reinterpret_cast<const float4*>(base3 + 16 * nn);
        part.x = fmaf(a[0][nn], v.x, part.x);
        part.y = fmaf(a[1][nn], v.y, part.y);
        part.z = fmaf(a[2][nn], v.z, part.z);
        part.w = fmaf(a[3][nn], v.w, part.w);
    }
    const float4 L3 = reinterpret_cast<const float4*>(l3)[j];
    float p = part.x * L3.x + part.y * L3.y + part.z * L3.z + part.w * L3.w;

    p += __shfl_xor(p, 1);
    p += __shfl_xor(p, 2);

    if (s < n && j == 0) out[s] = p;
}

extern "C" void kernel_launch(void* const* d_in, const int* in_sizes, int n_in,
                              void* d_out, int out_size, void* d_ws, size_t ws_size,
                              hipStream_t stream)
{
    const int*   idx = (const int*)  d_in[0];
    const float* c0  = (const float*)d_in[1];
    const float* l0  = (const float*)d_in[2];
    const float* c1  = (const float*)d_in[3];
    const float* l1  = (const float*)d_in[4];
    const float* c2  = (const float*)d_in[5];
    const float* l2  = (const float*)d_in[6];
    const float* c3  = (const float*)d_in[7];
    const float* l3  = (const float*)d_in[8];
    float* out = (float*)d_out;

    const int n = out_size;                       // 500000

    if (ws_size >= 409600) {
        char* wsb = (char*)d_ws;
        hipLaunchKernelGGL(prescale_kernel, dim3(400), dim3(256), 0, stream,
                           c0, l0, c1, l1, c2, l2, c3, l3, wsb);
        const int waves  = (n + 63) / 64;         // 7813
        const int blocks = (waves + 3) / 4;       // 1954
        hipLaunchKernelGGL(mfma_chain, dim3(blocks), dim3(256), 0, stream,
                           idx, wsb, out, n);
    } else {
        const int grid = (n + 63) / 64;
        hipLaunchKernelGGL(chain_kernel_fb, dim3(grid), dim3(256), 0, stream,
                           idx, c0, l0, c1, l1, c2, l2, c3, l3, out, n);
    }
}

// Round 17
// 48.926 us; speedup vs baseline: 1.4777x; 1.1289x over previous
//
#include <hip/hip_runtime.h>

// BayesTensorRing via paired 32x32x16 MFMA: out[s]=trace(M0'M1'M2'M3').
// Two samples per MFMA pair (block-diag); trace = per-lane pk-dot of X,Z diag
// entries + DPP funnel. Ladder: 72us (VMEM-inst halved, R15) -> 54 -> 51 (VALU
// cuts, R16). R17: occupancy push — R16 ran at 31% occupancy (~2.5 waves/SIMD;
// 4-state pipeline = 64 operand VGPRs + 48 accum). Cut to 2 states (-32 VGPR),
// __launch_bounds__(256,6) to cap allocation; rely on wave TLP for latency
// hiding (m114) instead of deep per-wave prefetch.
//
// Layouts (verified R15/R16 pass): A[row=l&31][k=8j+4(l>>5)+i], B[col same],
// C/D: col=l&31, row=(reg&3)+8(reg>>2)+4(l>>5). ws granule order: lane reads
// 16B at slice byte ((l>>5)*16+(l&15))*16, slice select by lane bit4.
// ws: W0@0 | W1@102400 | W2@204800 | W3@307200 (f16, 512B slices). 409600B.

typedef _Float16 f16x8  __attribute__((ext_vector_type(8)));
typedef _Float16 f16x2  __attribute__((ext_vector_type(2)));
typedef float    f32x16 __attribute__((ext_vector_type(16)));
typedef float    f32x2  __attribute__((ext_vector_type(2)));

#define DEV static __device__ __forceinline__

template<int CTRL>
DEV float dppmov(float x)
{
    return __int_as_float(__builtin_amdgcn_update_dpp(
        0, __float_as_int(x), CTRL, 0xF, 0xF, true));
}

DEV f16x8 ldg16s(const _Float16* sbase, int voff)
{
    f16x8 d;
    asm volatile("global_load_dwordx4 %0, %1, %2"
                 : "=&v"(d) : "v"(voff), "s"(sbase) : "memory");
    return d;
}

DEV f32x2 pkfma(f32x2 a, f32x2 b, f32x2 c)
{
    f32x2 d;
    asm("v_pk_fma_f32 %0, %1, %2, %3" : "=v"(d) : "v"(a), "v"(b), "v"(c));
    return d;
}

#define WAITV(N) asm volatile("s_waitcnt vmcnt(" #N ")" ::: "memory")
#define RL(v, l) __builtin_amdgcn_readlane((v), (l))

union Acc16 { f32x16 v; f32x2 p[8]; };

__global__ __launch_bounds__(256, 6)
void mfma_chain(const int* __restrict__ idx, const char* __restrict__ wsb,
                float* __restrict__ out, int n)
{
    const _Float16* W0 = (const _Float16*)(wsb);
    const _Float16* W1 = (const _Float16*)(wsb + 102400);
    const _Float16* W2 = (const _Float16*)(wsb + 204800);
    const _Float16* W3 = (const _Float16*)(wsb + 307200);

    const int lane = threadIdx.x & 63;
    const int wv   = (blockIdx.x << 2) | (threadIdx.x >> 6);
    const int s0   = __builtin_amdgcn_readfirstlane(wv << 6);
    if (s0 >= n) return;
    const int cnt  = (n - s0 < 64) ? (n - s0) : 64;             // 64 or 32

    const int voff = ((lane >> 5) << 8) + ((lane & 15) << 4);   // in-slice byte off
    const int hiI  = (lane >> 4) & 1;       // serves sample t+1
    const bool clow = (lane & 31) < 16;     // col<16 -> sample t diag block

    const int lc = lane < cnt ? lane : cnt - 1;
    const int4 vidx = *(const int4*)(idx + 4l * (s0 + lc));
    const int vo0 = (vidx.x << 9), vo1 = (vidx.y << 9);
    const int vo2 = (vidx.z << 9), vo3 = (vidx.w << 9);

    float res = 0.f;
    const f32x16 zacc = {};

    #define ISSUE(S, t) {                                                    \
        const int tb   = (t) <= 62 ? (t) : 62;                               \
        const int tsel = tb | hiI;                                           \
        S##a0 = ldg16s(W0, __shfl(vo0, tsel) + voff);                        \
        S##b1 = ldg16s(W1, __shfl(vo1, tsel) + voff);                        \
        S##b2 = ldg16s(W2, __shfl(vo2, tsel) + voff);                        \
        S##a3 = ldg16s(W3, __shfl(vo3, tsel) + voff);                        \
    }

    #define COMP(S, t) {                                                     \
        WAITV(4);                                                            \
        __builtin_amdgcn_sched_barrier(0);                                   \
        Acc16 X, Z;                                                          \
        X.v = __builtin_amdgcn_mfma_f32_32x32x16_f16(S##a0, S##b1, zacc, 0, 0, 0); \
        Z.v = __builtin_amdgcn_mfma_f32_32x32x16_f16(S##a3, S##b2, zacc, 0, 0, 0); \
        f32x2 zero2 = {0.f, 0.f};                                            \
        f32x2 dlo = pkfma(X.p[0], Z.p[0], zero2);                            \
        dlo = pkfma(X.p[1], Z.p[1], dlo);                                    \
        dlo = pkfma(X.p[2], Z.p[2], dlo);                                    \
        dlo = pkfma(X.p[3], Z.p[3], dlo);                                    \
        f32x2 dhi = pkfma(X.p[4], Z.p[4], zero2);                            \
        dhi = pkfma(X.p[5], Z.p[5], dhi);                                    \
        dhi = pkfma(X.p[6], Z.p[6], dhi);                                    \
        dhi = pkfma(X.p[7], Z.p[7], dhi);                                    \
        const float sA = clow ? dlo[0] : dhi[0];                             \
        const float sB = clow ? dlo[1] : dhi[1];                             \
        float p = sA + sB;                                                   \
        p += dppmov<0x111>(p);                                               \
        p += dppmov<0x112>(p);                                               \
        p += dppmov<0x114>(p);                                               \
        p += dppmov<0x118>(p);                                               \
        p += __shfl_xor(p, 32);                                              \
        const int pa = RL(__float_as_int(p), 15);                            \
        const int pb = RL(__float_as_int(p), 31);                            \
        res = (lane == (t))     ? __int_as_float(pa) : res;                  \
        res = (lane == (t) + 1) ? __int_as_float(pb) : res;                  \
    }

    f16x8 Aa0, Ab1, Ab2, Aa3;
    f16x8 Ba0, Bb1, Bb2, Ba3;

    ISSUE(A, 0); ISSUE(B, 2);

    const int cntR = (cnt + 3) & ~3;     // 64 or 32
    for (int t = 0; t + 4 <= cntR; t += 4) {
        COMP(A, t);     ISSUE(A, t + 4);
        COMP(B, t + 2); ISSUE(B, t + 6);
    }

    if (lane < cnt) out[s0 + lane] = res;

    #undef ISSUE
    #undef COMP
}

// Prescale into granule order (same as R15/R16, verified). pr: g=pr>>2, w=pr&3;
// h=g>>4, q=g&15; k0=8*(w>>1)+4*h+2*(w&1); dst slice pos g*8+2w.
__global__ __launch_bounds__(256)
void prescale_kernel(const float* __restrict__ cr0, const float* __restrict__ lm0,
                     const float* __restrict__ cr1, const float* __restrict__ lm1,
                     const float* __restrict__ cr2, const float* __restrict__ lm2,
                     const float* __restrict__ cr3, const float* __restrict__ lm3,
                     char* __restrict__ wsb)
{
    _Float16* W0 = (_Float16*)(wsb);
    _Float16* W1 = (_Float16*)(wsb + 102400);
    _Float16* W2 = (_Float16*)(wsb + 204800);
    _Float16* W3 = (_Float16*)(wsb + 307200);

    const int bx  = blockIdx.x;
    const int d   = bx / 100;
    const int gid = (bx % 100) * 256 + threadIdx.x;
    const int i   = gid >> 7;
    const int pr  = gid & 127;

    const int g  = pr >> 2, w = pr & 3;
    const int h  = g >> 4,  q = g & 15;
    const int k0 = 8 * (w >> 1) + 4 * h + 2 * (w & 1);
    const int dstpos = i * 256 + g * 8 + 2 * w;

    if (d == 0 || d == 2) {
        const float* cp = (d == 0) ? cr0 : cr2;
        const float* lp = (d == 0) ? lm0 : lm2;
        _Float16*    Wt = (d == 0) ? W0 : W2;
        const float2 v = *(const float2*)(cp + i * 256 + q * 16 + k0);
        f16x2 o; o[0] = (_Float16)(v.x * lp[k0]); o[1] = (_Float16)(v.y * lp[k0 + 1]);
        *(f16x2*)(Wt + dstpos) = o;
    } else {
        const float* cp = (d == 1) ? cr1 : cr3;
        const float* lp = (d == 1) ? lm1 : lm3;
        _Float16*    Wt = (d == 1) ? W1 : W3;
        const float a = cp[i * 256 + k0 * 16 + q]       * lp[q];
        const float b = cp[i * 256 + (k0 + 1) * 16 + q] * lp[q];
        f16x2 o; o[0] = (_Float16)a; o[1] = (_Float16)b;
        *(f16x2*)(Wt + dstpos) = o;
    }
}

// ---------------- fallback (no workspace): R5 DPP vector kernel ----------------
template<int CTRL>
DEV float dppf(float x)
{
    return __int_as_float(__builtin_amdgcn_update_dpp(
        0, __float_as_int(x), CTRL, 0xF, 0xF, true));
}

DEV void mm16g_lam(const float (&a)[4][16], float (&b)[4][16],
                   const float* __restrict__ m, const float* __restrict__ lam)
{
    const float4* m4 = reinterpret_cast<const float4*>(m);
    float4 lv[4];
#pragma unroll
    for (int q = 0; q < 4; ++q) lv[q] = reinterpret_cast<const float4*>(lam)[q];
#pragma unroll
    for (int nn = 0; nn < 16; ++nn) {
        float mrow[16];
#pragma unroll
        for (int q = 0; q < 4; ++q) {
            float4 v = m4[4 * nn + q];
            v.x *= lv[q].x; v.y *= lv[q].y; v.z *= lv[q].z; v.w *= lv[q].w;
            mrow[4*q+0] = v.x; mrow[4*q+1] = v.y;
            mrow[4*q+2] = v.z; mrow[4*q+3] = v.w;
        }
#pragma unroll
        for (int r = 0; r < 4; ++r) {
            const float av = a[r][nn];
            if (nn == 0) {
#pragma unroll
                for (int k = 0; k < 16; ++k) b[r][k] = av * mrow[k];
            } else {
#pragma unroll
                for (int k = 0; k < 16; ++k) b[r][k] = fmaf(av, mrow[k], b[r][k]);
            }
        }
    }
}

__global__ __launch_bounds__(256)
void chain_kernel_fb(const int* __restrict__ idx,
                     const float* __restrict__ c0, const float* __restrict__ l0,
                     const float* __restrict__ c1, const float* __restrict__ l1,
                     const float* __restrict__ c2, const float* __restrict__ l2,
                     const float* __restrict__ c3, const float* __restrict__ l3,
                     float* __restrict__ out, int n)
{
    const int tid  = threadIdx.x;
    const int slot = tid >> 2;
    const int j    = tid & 3;
    const int s    = blockIdx.x * 64 + slot;
    const int sc   = s < n ? s : n - 1;

    const int4 ix = *reinterpret_cast<const int4*>(idx + 4l * sc);

    float a[4][16], b[4][16];
    {
        const float4* src = reinterpret_cast<const float4*>(c0 + 256l * ix.x) + 16 * j;
#pragma unroll
        for (int t = 0; t < 16; ++t) {
            float4 v = src[t];
            const float4 L = reinterpret_cast<const float4*>(l0)[t & 3];
            const int r = t >> 2, c = (t & 3) * 4;
            a[r][c+0] = v.x * L.x; a[r][c+1] = v.y * L.y;
            a[r][c+2] = v.z * L.z; a[r][c+3] = v.w * L.w;
        }
    }

    mm16g_lam(a, b, c1 + 256l * ix.y, l1);
    mm16g_lam(b, a, c2 + 256l * ix.z, l2);

    float4 part = make_float4(0.f, 0.f, 0.f, 0.f);
    const float* base3 = c3 + 256l * ix.w + 4 * j;
#pragma unroll
    for (int nn = 0; nn < 16; ++nn) {
        const float4 v = *reinterpret_cast<const float4*>(base3 + 16 * nn);
        part.x = fmaf(a[0][nn], v.x, part.x);
        part.y = fmaf(a[1][nn], v.y, part.y);
        part.z = fmaf(a[2][nn], v.z, part.z);
        part.w = fmaf(a[3][nn], v.w, part.w);
    }
    const float4 L3 = reinterpret_cast<const float4*>(l3)[j];
    float p = part.x * L3.x + part.y * L3.y + part.z * L3.z + part.w * L3.w;

    p += __shfl_xor(p, 1);
    p += __shfl_xor(p, 2);

    if (s < n && j == 0) out[s] = p;
}

extern "C" void kernel_launch(void* const* d_in, const int* in_sizes, int n_in,
                              void* d_out, int out_size, void* d_ws, size_t ws_size,
                              hipStream_t stream)
{
    const int*   idx = (const int*)  d_in[0];
    const float* c0  = (const float*)d_in[1];
    const float* l0  = (const float*)d_in[2];
    const float* c1  = (const float*)d_in[3];
    const float* l1  = (const float*)d_in[4];
    const float* c2  = (const float*)d_in[5];
    const float* l2  = (const float*)d_in[6];
    const float* c3  = (const float*)d_in[7];
    const float* l3  = (const float*)d_in[8];
    float* out = (float*)d_out;

    const int n = out_size;                       // 500000

    if (ws_size >= 409600) {
        char* wsb = (char*)d_ws;
        hipLaunchKernelGGL(prescale_kernel, dim3(400), dim3(256), 0, stream,
                           c0, l0, c1, l1, c2, l2, c3, l3, wsb);
        const int waves  = (n + 63) / 64;         // 7813
        const int blocks = (waves + 3) / 4;       // 1954
        hipLaunchKernelGGL(mfma_chain, dim3(blocks), dim3(256), 0, stream,
                           idx, wsb, out, n);
    } else {
        const int grid = (n + 63) / 64;
        hipLaunchKernelGGL(chain_kernel_fb, dim3(grid), dim3(256), 0, stream,
                           idx, c0, l0, c1, l1, c2, l2, c3, l3, out, n);
    }
}